// Round 3
// baseline (1140.917 us; speedup 1.0000x reference)
//
#include <hip/hip_runtime.h>

#define Hdim 1024
#define Bdim 32
#define Sdim 2048

typedef __attribute__((ext_vector_type(8))) __bf16 bf16x8;
typedef __attribute__((ext_vector_type(4))) __bf16 bf16x4;
typedef __attribute__((ext_vector_type(4))) float f32x4;

#define GLOAD_LDS16(gp, lp)                                                              \
  __builtin_amdgcn_global_load_lds(                                                     \
      (const __attribute__((address_space(1))) unsigned int*)(gp),                      \
      (__attribute__((address_space(3))) unsigned int*)(lp), 16, 0, 0)

// ---------------------------------------------------------------------------
// Fused prep: blocks [0,4)=qc GEMV, [4,516)=Ua->bf16 relayout, [516,33284)=key->bf16.
// qc blocks first so the long-running ones start earliest and hide under the stream.
__global__ __launch_bounds__(256) void prep_kernel(const float* __restrict__ key,
                                                   const float* __restrict__ Ua,
                                                   const float* __restrict__ q,
                                                   const float* __restrict__ Wa,
                                                   const float* __restrict__ Wab,
                                                   const float* __restrict__ Uab,
                                                   __bf16* __restrict__ bkey,
                                                   __bf16* __restrict__ ubt,
                                                   float* __restrict__ qc) {
  const int bid = blockIdx.x;
  const int tid = threadIdx.x;
  if (bid < 4) {
    // qc[b,h] = q[b]@Wa + Wa_b + Ua_b ; thread owns one h, all 32 b. Wa read once.
    int h = bid * 256 + tid;
    float init = Wab[h] + Uab[h];
    float acc[32];
#pragma unroll
    for (int b = 0; b < 32; ++b) acc[b] = init;
    for (int i = 0; i < Hdim; ++i) {
      float wa = Wa[i * Hdim + h];  // coalesced across threads
#pragma unroll
      for (int b = 0; b < 32; ++b)
        acc[b] = fmaf(q[b * Hdim + i], wa, acc[b]);  // q addr is wave-uniform -> s_load
    }
#pragma unroll
    for (int b = 0; b < 32; ++b) qc[b * Hdim + h] = acc[b];
  } else if (bid < 516) {
    // Ua (k-major fp32) -> bf16 [ntile][k8][n][8]
    int du = (bid - 4) * 256 + tid;  // 0..131071
    int n  = du & 127;
    int k8 = (du >> 7) & 127;
    int nt = du >> 14;
    int ng = nt * 128 + n;
    bf16x8 t;
#pragma unroll
    for (int j = 0; j < 8; ++j)
      t[j] = (__bf16)Ua[(k8 * 8 + j) * Hdim + ng];
    *(bf16x8*)(ubt + (size_t)du * 8) = t;
  } else {
    // key fp32 -> bf16, same layout, 8 elems/thread
    size_t idx = (size_t)(bid - 516) * 256 + tid;
    const float4* src = (const float4*)(key + idx * 8);
    float4 f0 = src[0], f1 = src[1];
    bf16x8 t;
    t[0] = (__bf16)f0.x; t[1] = (__bf16)f0.y; t[2] = (__bf16)f0.z; t[3] = (__bf16)f0.w;
    t[4] = (__bf16)f1.x; t[5] = (__bf16)f1.y; t[6] = (__bf16)f1.z; t[7] = (__bf16)f1.w;
    *(bf16x8*)(bkey + idx * 8) = t;
  }
}

// ---------------------------------------------------------------------------
// Fused score GEMM: 128x128 tile, BK=64 (16 K-iters -> half the barrier drains),
// bf16 MFMA 16x16x32. A tile [k8][row][8] 16 KiB + B tile [k8][n][8] 16 KiB.
// XCD swizzle: all 8 nt-blocks of one mt share an XCD (blockIdx%8 const per mt).
__global__ __launch_bounds__(256) void gemm_scores_bf16_kernel(const __bf16* __restrict__ bkey,
                                                               const __bf16* __restrict__ ubt,
                                                               const float* __restrict__ qc,
                                                               const float* __restrict__ va,
                                                               float* __restrict__ part) {
  __shared__ __align__(16) __bf16 ABs[16384];  // [0,8192)=A, [8192,16384)=B; epilogue reuses as qc floats
  __shared__ float red[256];

  const int tid  = threadIdx.x;
  const int w    = tid >> 6;
  const int lane = tid & 63;
  const int quad = lane >> 4;
  const int l16  = lane & 15;

  const int l   = blockIdx.x;
  const int xcd = l & 7;
  const int i2  = l >> 3;
  const int mt  = xcd * 64 + (i2 >> 3);  // 0..511
  const int nt  = i2 & 7;                // 0..7

  const int r0 = mt * 128;
  const int n0 = nt * 128;
  const int wm = (w & 1) * 64;
  const int wn = (w >> 1) * 64;

  __bf16* As = ABs;
  __bf16* Bs = ABs + 8192;

  f32x4 acc[4][4] = {};

  for (int kc = 0; kc < Hdim; kc += 64) {
    // stage A: 128 rows x 64 k bf16 (16 KiB), [k8][row][8]
#pragma unroll
    for (int it = 0; it < 4; ++it) {
      int u  = it * 256 + tid;  // u = k8*128 + row, k8 in 0..7
      int k8 = u >> 7, row = u & 127;
      GLOAD_LDS16(bkey + (size_t)(r0 + row) * Hdim + kc + k8 * 8, As + u * 8);
    }
    // stage B: 128 n x 64 k bf16 (16 KiB), fully contiguous source
#pragma unroll
    for (int it = 0; it < 4; ++it) {
      int u = it * 256 + tid;  // u = k8*128 + n
      GLOAD_LDS16(ubt + ((size_t)nt * 16384 + (kc >> 3) * 128 + u) * 8, Bs + u * 8);
    }
    __syncthreads();

#pragma unroll
    for (int kk = 0; kk < 2; ++kk) {
      bf16x8 afr[4], bfr[4];
#pragma unroll
      for (int i = 0; i < 4; ++i)
        afr[i] = *(const bf16x8*)&As[((kk * 4 + quad) * 128 + wm + i * 16 + l16) * 8];
#pragma unroll
      for (int j = 0; j < 4; ++j)
        bfr[j] = *(const bf16x8*)&Bs[((kk * 4 + quad) * 128 + wn + j * 16 + l16) * 8];
#pragma unroll
      for (int i = 0; i < 4; ++i)
#pragma unroll
        for (int j = 0; j < 4; ++j)
          acc[i][j] = __builtin_amdgcn_mfma_f32_16x16x32_bf16(afr[i], bfr[j], acc[i][j], 0, 0, 0);
    }
    __syncthreads();
  }

  // stage qc tile (32 b-rows x 128 n-cols) into LDS (A region, 16 KiB >= 16 KiB)
  float* qcs = (float*)ABs;
#pragma unroll
  for (int it = 0; it < 16; ++it) {
    int u = it * 256 + tid;
    qcs[u] = qc[(u >> 7) * Hdim + n0 + (u & 127)];
  }
  __syncthreads();

  float vav[4];
#pragma unroll
  for (int j = 0; j < 4; ++j) vav[j] = va[n0 + wn + j * 16 + l16];

  // C/D layout (m89): col = lane&15 (n), row = quad*4 + reg (m)
#pragma unroll
  for (int i = 0; i < 4; ++i) {
#pragma unroll
    for (int rg = 0; rg < 4; ++rg) {
      int b = (i & 1) * 16 + quad * 4 + rg;
      float sum = 0.f;
#pragma unroll
      for (int j = 0; j < 4; ++j) {
        float v = acc[i][j][rg] + qcs[b * 128 + wn + j * 16 + l16];
        v = fminf(fmaxf(v, -15.f), 15.f);
        float e = __expf(2.f * v);
        sum += (e - 1.f) * __builtin_amdgcn_rcpf(e + 1.f) * vav[j];
      }
#pragma unroll
      for (int off = 1; off < 16; off <<= 1)
        sum += __shfl_xor(sum, off, 64);
      if (l16 == 0)
        red[(wm + i * 16 + quad * 4 + rg) * 2 + (w >> 1)] = sum;
    }
  }
  __syncthreads();
  if (tid < 128)
    part[(size_t)(r0 + tid) * 8 + nt] = red[tid * 2] + red[tid * 2 + 1];
}

// ---------------------------------------------------------------------------
// Fallback fp32-A GEMM (no bkey in ws)
__global__ __launch_bounds__(256) void gemm_scores_kernel(const float* __restrict__ key,
                                                          const __bf16* __restrict__ ubt,
                                                          const float* __restrict__ qc,
                                                          const float* __restrict__ va,
                                                          float* __restrict__ part) {
  __shared__ __align__(16) float AsQ[4096];
  __shared__ __align__(16) __bf16 Bs[4096];
  __shared__ float red[256];

  const int tid  = threadIdx.x;
  const int w    = tid >> 6;
  const int lane = tid & 63;
  const int quad = lane >> 4;
  const int l16  = lane & 15;
  const int l   = blockIdx.x;
  const int xcd = l & 7;
  const int i2  = l >> 3;
  const int mt  = xcd * 64 + (i2 >> 3);
  const int nt  = i2 & 7;
  const int r0 = mt * 128;
  const int n0 = nt * 128;
  const int wm = (w & 1) * 64;
  const int wn = (w >> 1) * 64;

  f32x4 acc[4][4] = {};

  for (int kc = 0; kc < Hdim; kc += 32) {
#pragma unroll
    for (int it = 0; it < 4; ++it) {
      int u  = it * 256 + tid;
      int k4 = u >> 7, row = u & 127;
      GLOAD_LDS16(key + (size_t)(r0 + row) * Hdim + kc + k4 * 4, AsQ + u * 4);
    }
#pragma unroll
    for (int it = 0; it < 2; ++it) {
      int u = it * 256 + tid;
      GLOAD_LDS16(ubt + ((size_t)nt * 16384 + (kc >> 3) * 128 + u) * 8, Bs + u * 8);
    }
    __syncthreads();

    bf16x8 bfr[4];
#pragma unroll
    for (int j = 0; j < 4; ++j)
      bfr[j] = *(const bf16x8*)&Bs[(quad * 128 + wn + j * 16 + l16) * 8];

    bf16x8 afr[4];
#pragma unroll
    for (int i = 0; i < 4; ++i) {
      int ml = wm + i * 16 + l16;
      float4 f0 = *(const float4*)&AsQ[((quad * 2) * 128 + ml) * 4];
      float4 f1 = *(const float4*)&AsQ[((quad * 2 + 1) * 128 + ml) * 4];
      bf16x8 a;
      a[0] = (__bf16)f0.x; a[1] = (__bf16)f0.y; a[2] = (__bf16)f0.z; a[3] = (__bf16)f0.w;
      a[4] = (__bf16)f1.x; a[5] = (__bf16)f1.y; a[6] = (__bf16)f1.z; a[7] = (__bf16)f1.w;
      afr[i] = a;
    }

#pragma unroll
    for (int i = 0; i < 4; ++i)
#pragma unroll
      for (int j = 0; j < 4; ++j)
        acc[i][j] = __builtin_amdgcn_mfma_f32_16x16x32_bf16(afr[i], bfr[j], acc[i][j], 0, 0, 0);

    __syncthreads();
  }

#pragma unroll
  for (int it = 0; it < 16; ++it) {
    int u = it * 256 + tid;
    AsQ[u] = qc[(u >> 7) * Hdim + n0 + (u & 127)];
  }
  __syncthreads();

  float vav[4];
#pragma unroll
  for (int j = 0; j < 4; ++j) vav[j] = va[n0 + wn + j * 16 + l16];

#pragma unroll
  for (int i = 0; i < 4; ++i) {
#pragma unroll
    for (int rg = 0; rg < 4; ++rg) {
      int b = (i & 1) * 16 + quad * 4 + rg;
      float sum = 0.f;
#pragma unroll
      for (int j = 0; j < 4; ++j) {
        float v = acc[i][j][rg] + AsQ[b * 128 + wn + j * 16 + l16];
        v = fminf(fmaxf(v, -15.f), 15.f);
        float e = __expf(2.f * v);
        sum += (e - 1.f) * __builtin_amdgcn_rcpf(e + 1.f) * vav[j];
      }
#pragma unroll
      for (int off = 1; off < 16; off <<= 1)
        sum += __shfl_xor(sum, off, 64);
      if (l16 == 0)
        red[(wm + i * 16 + quad * 4 + rg) * 2 + (w >> 1)] = sum;
    }
  }
  __syncthreads();
  if (tid < 128)
    part[(size_t)(r0 + tid) * 8 + nt] = red[tid * 2] + red[tid * 2 + 1];
}

// ---------------------------------------------------------------------------
__global__ __launch_bounds__(256) void softmax_kernel(const float* __restrict__ part,
                                                      float* __restrict__ dout) {
  int b = blockIdx.x, t = threadIdx.x;
  int w = t >> 6, lane = t & 63;
  __shared__ float red1[4], red2[4];
  float sc[8];
  float m = -1e30f;
#pragma unroll
  for (int c = 0; c < 8; ++c) {
    int s = c * 256 + t;
    const float4* p = (const float4*)&part[(size_t)(s * 32 + b) * 8];
    float4 p0 = p[0], p1 = p[1];
    float v = ((p0.x + p0.y) + (p0.z + p0.w)) + ((p1.x + p1.y) + (p1.z + p1.w));
    sc[c] = v;
    m = fmaxf(m, v);
  }
#pragma unroll
  for (int off = 1; off < 64; off <<= 1) m = fmaxf(m, __shfl_xor(m, off, 64));
  if (lane == 0) red1[w] = m;
  __syncthreads();
  m = fmaxf(fmaxf(red1[0], red1[1]), fmaxf(red1[2], red1[3]));
  float sum = 0.f;
#pragma unroll
  for (int c = 0; c < 8; ++c) { sc[c] = __expf(sc[c] - m); sum += sc[c]; }
#pragma unroll
  for (int off = 1; off < 64; off <<= 1) sum += __shfl_xor(sum, off, 64);
  if (lane == 0) red2[w] = sum;
  __syncthreads();
  float inv = 1.f / (red2[0] + red2[1] + red2[2] + red2[3]);
#pragma unroll
  for (int c = 0; c < 8; ++c)
    dout[32768 + b * 2048 + c * 256 + t] = sc[c] * inv;
}

// ---------------------------------------------------------------------------
// context partials from bf16 key: cpart[sc][b][h] = sum_{s in 128-chunk} w[b,s]*bkey[s,b,h]
__global__ __launch_bounds__(256) void ctx_part_bf16_kernel(const __bf16* __restrict__ bkey,
                                                            const float* __restrict__ dout,
                                                            float* __restrict__ cpart) {
  int sc = blockIdx.x;  // 0..15
  int b  = blockIdx.y;  // 0..31
  int t  = threadIdx.x;
  float4 acc = make_float4(0.f, 0.f, 0.f, 0.f);
  int s0 = sc * 128;
#pragma unroll 4
  for (int s = s0; s < s0 + 128; ++s) {
    float wgt = dout[32768 + b * 2048 + s];
    bf16x4 kv = *(const bf16x4*)(bkey + (((size_t)(s * 32 + b)) << 10) + t * 4);
    acc.x = fmaf(wgt, (float)kv[0], acc.x);
    acc.y = fmaf(wgt, (float)kv[1], acc.y);
    acc.z = fmaf(wgt, (float)kv[2], acc.z);
    acc.w = fmaf(wgt, (float)kv[3], acc.w);
  }
  *(float4*)&cpart[((size_t)(sc * 32 + b) << 10) + t * 4] = acc;
}

// fallback fp32 version (64-s chunks, 32 chunks)
__global__ __launch_bounds__(256) void ctx_part_kernel(const float* __restrict__ key,
                                                       const float* __restrict__ dout,
                                                       float* __restrict__ cpart) {
  int sc = blockIdx.x;
  int b  = blockIdx.y;
  int t  = threadIdx.x;
  float4 acc = make_float4(0.f, 0.f, 0.f, 0.f);
  int s0 = sc * 64;
#pragma unroll 8
  for (int s = s0; s < s0 + 64; ++s) {
    float wgt = dout[32768 + b * 2048 + s];
    float4 k4 = *(const float4*)&key[((size_t)(s * 32 + b) << 10) + t * 4];
    acc.x = fmaf(wgt, k4.x, acc.x);
    acc.y = fmaf(wgt, k4.y, acc.y);
    acc.z = fmaf(wgt, k4.z, acc.z);
    acc.w = fmaf(wgt, k4.w, acc.w);
  }
  *(float4*)&cpart[((size_t)(sc * 32 + b) << 10) + t * 4] = acc;
}

__global__ __launch_bounds__(256) void ctx_reduce_kernel(const float* __restrict__ cpart,
                                                         float* __restrict__ dout, int nc) {
  int o = blockIdx.x * 256 + threadIdx.x;
  int b = o >> 10, h = o & 1023;
  float s = 0.f;
  for (int sc = 0; sc < nc; ++sc)
    s += cpart[((size_t)(sc * 32 + b) << 10) + h];
  dout[o] = s;
}

// ---------------------------------------------------------------------------
extern "C" void kernel_launch(void* const* d_in, const int* in_sizes, int n_in,
                              void* d_out, int out_size, void* d_ws, size_t ws_size,
                              hipStream_t stream) {
  const float* q   = (const float*)d_in[0];
  const float* key = (const float*)d_in[1];
  const float* Waw = (const float*)d_in[2];
  const float* Wab = (const float*)d_in[3];
  const float* Uaw = (const float*)d_in[4];
  const float* Uab = (const float*)d_in[5];
  const float* vaw = (const float*)d_in[6];
  float* out = (float*)d_out;  // [0,32768): context ; [32768,98304): weights

  char* ws = (char*)d_ws;
  float*  qc    = (float*)(ws);                                 // 128 KiB
  __bf16* ubt   = (__bf16*)(ws + 131072);                       // 2 MiB
  float*  part  = (float*)(ws + 131072 + 2097152);              // 2 MiB
  float*  cpart = (float*)(ws + 131072 + 2097152 + 2097152);    // 4 MiB
  __bf16* bkey  = (__bf16*)(ws + 131072 + 2097152 + 2097152 + 4194304);  // 128 MiB
  const size_t need = 131072ull + 2097152 + 2097152 + 4194304 + 134217728;

  if (ws_size >= need) {
    prep_kernel<<<33284, 256, 0, stream>>>(key, Uaw, q, Waw, Wab, Uab, bkey, ubt, qc);
    gemm_scores_bf16_kernel<<<4096, 256, 0, stream>>>(bkey, ubt, qc, vaw, part);
    softmax_kernel<<<32, 256, 0, stream>>>(part, out);
    ctx_part_bf16_kernel<<<dim3(16, 32), 256, 0, stream>>>(bkey, out, cpart);
    ctx_reduce_kernel<<<128, 256, 0, stream>>>(cpart, out, 16);
  } else {
    prep_kernel<<<516, 256, 0, stream>>>(key, Uaw, q, Waw, Wab, Uab, bkey, ubt, qc);
    gemm_scores_kernel<<<4096, 256, 0, stream>>>(key, ubt, qc, vaw, part);
    softmax_kernel<<<32, 256, 0, stream>>>(part, out);
    ctx_part_kernel<<<dim3(32, 32), 256, 0, stream>>>(key, out, cpart);
    ctx_reduce_kernel<<<128, 256, 0, stream>>>(cpart, out, 32);
  }
}

// Round 4
// 727.808 us; speedup vs baseline: 1.5676x; 1.5676x over previous
//
#include <hip/hip_runtime.h>

#define Hdim 1024
#define Bdim 32
#define Sdim 2048

typedef __attribute__((ext_vector_type(8))) __bf16 bf16x8;
typedef __attribute__((ext_vector_type(4))) __bf16 bf16x4;
typedef __attribute__((ext_vector_type(4))) float f32x4;

#define GLOAD_LDS16(gp, lp)                                                              \
  __builtin_amdgcn_global_load_lds(                                                     \
      (const __attribute__((address_space(1))) unsigned int*)(gp),                      \
      (__attribute__((address_space(3))) unsigned int*)(lp), 16, 0, 0)

// ---------------------------------------------------------------------------
// key fp32 -> bf16, grid-stride: 8 independent 32B-chunks per thread (loads in
// flight), 4096 blocks x 256 thr x 8 chunks x 8 floats = 67.1M floats exactly.
__global__ __launch_bounds__(256) void convert_key_kernel(const float* __restrict__ key,
                                                          __bf16* __restrict__ bkey) {
  size_t tid0 = (size_t)blockIdx.x * 256 + threadIdx.x;
  const size_t stride = (size_t)4096 * 256;
#pragma unroll
  for (int c = 0; c < 8; ++c) {
    size_t idx = tid0 + (size_t)c * stride;
    const float4* src = (const float4*)(key + idx * 8);
    float4 f0 = src[0], f1 = src[1];
    bf16x8 t;
    t[0] = (__bf16)f0.x; t[1] = (__bf16)f0.y; t[2] = (__bf16)f0.z; t[3] = (__bf16)f0.w;
    t[4] = (__bf16)f1.x; t[5] = (__bf16)f1.y; t[6] = (__bf16)f1.z; t[7] = (__bf16)f1.w;
    *(bf16x8*)(bkey + idx * 8) = t;
  }
}

// ---------------------------------------------------------------------------
// Ua (H x H fp32, k-major) -> bf16 [ntile][k8][n][8] (R2 known-good)
__global__ __launch_bounds__(256) void convert_ua_kernel(const float* __restrict__ Ua,
                                                         __bf16* __restrict__ ubt) {
  int du = blockIdx.x * 256 + threadIdx.x;
  int n  = du & 127;
  int k8 = (du >> 7) & 127;
  int nt = du >> 14;
  int ng = nt * 128 + n;
  bf16x8 t;
#pragma unroll
  for (int j = 0; j < 8; ++j)
    t[j] = (__bf16)Ua[(k8 * 8 + j) * Hdim + ng];
  *(bf16x8*)(ubt + (size_t)du * 8) = t;
}

// ---------------------------------------------------------------------------
// qc[b,h] = q[b]@Wa + Wa_b + Ua_b  (R2 known-good: 128 blocks, unroll 16)
__global__ __launch_bounds__(256) void qc_kernel(const float* __restrict__ q,
                                                 const float* __restrict__ Wa,
                                                 const float* __restrict__ Wab,
                                                 const float* __restrict__ Uab,
                                                 float* __restrict__ qc) {
  int b = blockIdx.y;
  int h = blockIdx.x * 256 + threadIdx.x;
  float acc = Wab[h] + Uab[h];
  const float* qr = q + b * Hdim;
#pragma unroll 16
  for (int i = 0; i < Hdim; ++i)
    acc = fmaf(qr[i], Wa[i * Hdim + h], acc);
  qc[b * Hdim + h] = acc;
}

// ---------------------------------------------------------------------------
// Fused score GEMM: 128x128 tile, BK=64, bf16 MFMA 16x16x32, XCD swizzle.
__global__ __launch_bounds__(256) void gemm_scores_bf16_kernel(const __bf16* __restrict__ bkey,
                                                               const __bf16* __restrict__ ubt,
                                                               const float* __restrict__ qc,
                                                               const float* __restrict__ va,
                                                               float* __restrict__ part) {
  __shared__ __align__(16) __bf16 ABs[16384];  // [0,8192)=A, [8192,16384)=B; epilogue: qc floats
  __shared__ float red[256];

  const int tid  = threadIdx.x;
  const int w    = tid >> 6;
  const int lane = tid & 63;
  const int quad = lane >> 4;
  const int l16  = lane & 15;

  const int l   = blockIdx.x;
  const int xcd = l & 7;
  const int i2  = l >> 3;
  const int mt  = xcd * 64 + (i2 >> 3);  // 0..511 (8 nt-blocks of one mt share an XCD)
  const int nt  = i2 & 7;

  const int r0 = mt * 128;
  const int n0 = nt * 128;
  const int wm = (w & 1) * 64;
  const int wn = (w >> 1) * 64;

  __bf16* As = ABs;
  __bf16* Bs = ABs + 8192;

  f32x4 acc[4][4] = {};

  for (int kc = 0; kc < Hdim; kc += 64) {
#pragma unroll
    for (int it = 0; it < 4; ++it) {
      int u  = it * 256 + tid;  // u = k8*128 + row
      int k8 = u >> 7, row = u & 127;
      GLOAD_LDS16(bkey + (size_t)(r0 + row) * Hdim + kc + k8 * 8, As + u * 8);
    }
#pragma unroll
    for (int it = 0; it < 4; ++it) {
      int u = it * 256 + tid;  // u = k8*128 + n
      GLOAD_LDS16(ubt + ((size_t)nt * 16384 + (kc >> 3) * 128 + u) * 8, Bs + u * 8);
    }
    __syncthreads();

#pragma unroll
    for (int kk = 0; kk < 2; ++kk) {
      bf16x8 afr[4], bfr[4];
#pragma unroll
      for (int i = 0; i < 4; ++i)
        afr[i] = *(const bf16x8*)&As[((kk * 4 + quad) * 128 + wm + i * 16 + l16) * 8];
#pragma unroll
      for (int j = 0; j < 4; ++j)
        bfr[j] = *(const bf16x8*)&Bs[((kk * 4 + quad) * 128 + wn + j * 16 + l16) * 8];
#pragma unroll
      for (int i = 0; i < 4; ++i)
#pragma unroll
        for (int j = 0; j < 4; ++j)
          acc[i][j] = __builtin_amdgcn_mfma_f32_16x16x32_bf16(afr[i], bfr[j], acc[i][j], 0, 0, 0);
    }
    __syncthreads();
  }

  float* qcs = (float*)ABs;
#pragma unroll
  for (int it = 0; it < 16; ++it) {
    int u = it * 256 + tid;
    qcs[u] = qc[(u >> 7) * Hdim + n0 + (u & 127)];
  }
  __syncthreads();

  float vav[4];
#pragma unroll
  for (int j = 0; j < 4; ++j) vav[j] = va[n0 + wn + j * 16 + l16];

  // C/D layout (m89): col = lane&15 (n), row = quad*4 + reg (m)
#pragma unroll
  for (int i = 0; i < 4; ++i) {
#pragma unroll
    for (int rg = 0; rg < 4; ++rg) {
      int b = (i & 1) * 16 + quad * 4 + rg;
      float sum = 0.f;
#pragma unroll
      for (int j = 0; j < 4; ++j) {
        float v = acc[i][j][rg] + qcs[b * 128 + wn + j * 16 + l16];
        v = fminf(fmaxf(v, -15.f), 15.f);
        float e = __expf(2.f * v);
        sum += (e - 1.f) * __builtin_amdgcn_rcpf(e + 1.f) * vav[j];
      }
#pragma unroll
      for (int off = 1; off < 16; off <<= 1)
        sum += __shfl_xor(sum, off, 64);
      if (l16 == 0)
        red[(wm + i * 16 + quad * 4 + rg) * 2 + (w >> 1)] = sum;
    }
  }
  __syncthreads();
  if (tid < 128)
    part[(size_t)(r0 + tid) * 8 + nt] = red[tid * 2] + red[tid * 2 + 1];
}

// ---------------------------------------------------------------------------
// Fallback fp32-A GEMM (no bkey in ws)
__global__ __launch_bounds__(256) void gemm_scores_kernel(const float* __restrict__ key,
                                                          const __bf16* __restrict__ ubt,
                                                          const float* __restrict__ qc,
                                                          const float* __restrict__ va,
                                                          float* __restrict__ part) {
  __shared__ __align__(16) float AsQ[4096];
  __shared__ __align__(16) __bf16 Bs[4096];
  __shared__ float red[256];

  const int tid  = threadIdx.x;
  const int w    = tid >> 6;
  const int lane = tid & 63;
  const int quad = lane >> 4;
  const int l16  = lane & 15;
  const int l   = blockIdx.x;
  const int xcd = l & 7;
  const int i2  = l >> 3;
  const int mt  = xcd * 64 + (i2 >> 3);
  const int nt  = i2 & 7;
  const int r0 = mt * 128;
  const int n0 = nt * 128;
  const int wm = (w & 1) * 64;
  const int wn = (w >> 1) * 64;

  f32x4 acc[4][4] = {};

  for (int kc = 0; kc < Hdim; kc += 32) {
#pragma unroll
    for (int it = 0; it < 4; ++it) {
      int u  = it * 256 + tid;
      int k4 = u >> 7, row = u & 127;
      GLOAD_LDS16(key + (size_t)(r0 + row) * Hdim + kc + k4 * 4, AsQ + u * 4);
    }
#pragma unroll
    for (int it = 0; it < 2; ++it) {
      int u = it * 256 + tid;
      GLOAD_LDS16(ubt + ((size_t)nt * 16384 + (kc >> 3) * 128 + u) * 8, Bs + u * 8);
    }
    __syncthreads();

    bf16x8 bfr[4];
#pragma unroll
    for (int j = 0; j < 4; ++j)
      bfr[j] = *(const bf16x8*)&Bs[(quad * 128 + wn + j * 16 + l16) * 8];

    bf16x8 afr[4];
#pragma unroll
    for (int i = 0; i < 4; ++i) {
      int ml = wm + i * 16 + l16;
      float4 f0 = *(const float4*)&AsQ[((quad * 2) * 128 + ml) * 4];
      float4 f1 = *(const float4*)&AsQ[((quad * 2 + 1) * 128 + ml) * 4];
      bf16x8 a;
      a[0] = (__bf16)f0.x; a[1] = (__bf16)f0.y; a[2] = (__bf16)f0.z; a[3] = (__bf16)f0.w;
      a[4] = (__bf16)f1.x; a[5] = (__bf16)f1.y; a[6] = (__bf16)f1.z; a[7] = (__bf16)f1.w;
      afr[i] = a;
    }

#pragma unroll
    for (int i = 0; i < 4; ++i)
#pragma unroll
      for (int j = 0; j < 4; ++j)
        acc[i][j] = __builtin_amdgcn_mfma_f32_16x16x32_bf16(afr[i], bfr[j], acc[i][j], 0, 0, 0);

    __syncthreads();
  }

#pragma unroll
  for (int it = 0; it < 16; ++it) {
    int u = it * 256 + tid;
    AsQ[u] = qc[(u >> 7) * Hdim + n0 + (u & 127)];
  }
  __syncthreads();

  float vav[4];
#pragma unroll
  for (int j = 0; j < 4; ++j) vav[j] = va[n0 + wn + j * 16 + l16];

#pragma unroll
  for (int i = 0; i < 4; ++i) {
#pragma unroll
    for (int rg = 0; rg < 4; ++rg) {
      int b = (i & 1) * 16 + quad * 4 + rg;
      float sum = 0.f;
#pragma unroll
      for (int j = 0; j < 4; ++j) {
        float v = acc[i][j][rg] + AsQ[b * 128 + wn + j * 16 + l16];
        v = fminf(fmaxf(v, -15.f), 15.f);
        float e = __expf(2.f * v);
        sum += (e - 1.f) * __builtin_amdgcn_rcpf(e + 1.f) * vav[j];
      }
#pragma unroll
      for (int off = 1; off < 16; off <<= 1)
        sum += __shfl_xor(sum, off, 64);
      if (l16 == 0)
        red[(wm + i * 16 + quad * 4 + rg) * 2 + (w >> 1)] = sum;
    }
  }
  __syncthreads();
  if (tid < 128)
    part[(size_t)(r0 + tid) * 8 + nt] = red[tid * 2] + red[tid * 2 + 1];
}

// ---------------------------------------------------------------------------
__global__ __launch_bounds__(256) void softmax_kernel(const float* __restrict__ part,
                                                      float* __restrict__ dout) {
  int b = blockIdx.x, t = threadIdx.x;
  int w = t >> 6, lane = t & 63;
  __shared__ float red1[4], red2[4];
  float sc[8];
  float m = -1e30f;
#pragma unroll
  for (int c = 0; c < 8; ++c) {
    int s = c * 256 + t;
    const float4* p = (const float4*)&part[(size_t)(s * 32 + b) * 8];
    float4 p0 = p[0], p1 = p[1];
    float v = ((p0.x + p0.y) + (p0.z + p0.w)) + ((p1.x + p1.y) + (p1.z + p1.w));
    sc[c] = v;
    m = fmaxf(m, v);
  }
#pragma unroll
  for (int off = 1; off < 64; off <<= 1) m = fmaxf(m, __shfl_xor(m, off, 64));
  if (lane == 0) red1[w] = m;
  __syncthreads();
  m = fmaxf(fmaxf(red1[0], red1[1]), fmaxf(red1[2], red1[3]));
  float sum = 0.f;
#pragma unroll
  for (int c = 0; c < 8; ++c) { sc[c] = __expf(sc[c] - m); sum += sc[c]; }
#pragma unroll
  for (int off = 1; off < 64; off <<= 1) sum += __shfl_xor(sum, off, 64);
  if (lane == 0) red2[w] = sum;
  __syncthreads();
  float inv = 1.f / (red2[0] + red2[1] + red2[2] + red2[3]);
#pragma unroll
  for (int c = 0; c < 8; ++c)
    dout[32768 + b * 2048 + c * 256 + t] = sc[c] * inv;
}

// ---------------------------------------------------------------------------
__global__ __launch_bounds__(256) void ctx_part_bf16_kernel(const __bf16* __restrict__ bkey,
                                                            const float* __restrict__ dout,
                                                            float* __restrict__ cpart) {
  int sc = blockIdx.x;  // 0..15
  int b  = blockIdx.y;  // 0..31
  int t  = threadIdx.x;
  float4 acc = make_float4(0.f, 0.f, 0.f, 0.f);
  int s0 = sc * 128;
#pragma unroll 4
  for (int s = s0; s < s0 + 128; ++s) {
    float wgt = dout[32768 + b * 2048 + s];
    bf16x4 kv = *(const bf16x4*)(bkey + (((size_t)(s * 32 + b)) << 10) + t * 4);
    acc.x = fmaf(wgt, (float)kv[0], acc.x);
    acc.y = fmaf(wgt, (float)kv[1], acc.y);
    acc.z = fmaf(wgt, (float)kv[2], acc.z);
    acc.w = fmaf(wgt, (float)kv[3], acc.w);
  }
  *(float4*)&cpart[((size_t)(sc * 32 + b) << 10) + t * 4] = acc;
}

__global__ __launch_bounds__(256) void ctx_part_kernel(const float* __restrict__ key,
                                                       const float* __restrict__ dout,
                                                       float* __restrict__ cpart) {
  int sc = blockIdx.x;
  int b  = blockIdx.y;
  int t  = threadIdx.x;
  float4 acc = make_float4(0.f, 0.f, 0.f, 0.f);
  int s0 = sc * 64;
#pragma unroll 8
  for (int s = s0; s < s0 + 64; ++s) {
    float wgt = dout[32768 + b * 2048 + s];
    float4 k4 = *(const float4*)&key[((size_t)(s * 32 + b) << 10) + t * 4];
    acc.x = fmaf(wgt, k4.x, acc.x);
    acc.y = fmaf(wgt, k4.y, acc.y);
    acc.z = fmaf(wgt, k4.z, acc.z);
    acc.w = fmaf(wgt, k4.w, acc.w);
  }
  *(float4*)&cpart[((size_t)(sc * 32 + b) << 10) + t * 4] = acc;
}

__global__ __launch_bounds__(256) void ctx_reduce_kernel(const float* __restrict__ cpart,
                                                         float* __restrict__ dout, int nc) {
  int o = blockIdx.x * 256 + threadIdx.x;
  int b = o >> 10, h = o & 1023;
  float s = 0.f;
  for (int sc = 0; sc < nc; ++sc)
    s += cpart[((size_t)(sc * 32 + b) << 10) + h];
  dout[o] = s;
}

// ---------------------------------------------------------------------------
extern "C" void kernel_launch(void* const* d_in, const int* in_sizes, int n_in,
                              void* d_out, int out_size, void* d_ws, size_t ws_size,
                              hipStream_t stream) {
  const float* q   = (const float*)d_in[0];
  const float* key = (const float*)d_in[1];
  const float* Waw = (const float*)d_in[2];
  const float* Wab = (const float*)d_in[3];
  const float* Uaw = (const float*)d_in[4];
  const float* Uab = (const float*)d_in[5];
  const float* vaw = (const float*)d_in[6];
  float* out = (float*)d_out;  // [0,32768): context ; [32768,98304): weights

  char* ws = (char*)d_ws;
  float*  qc    = (float*)(ws);                                 // 128 KiB
  __bf16* ubt   = (__bf16*)(ws + 131072);                       // 2 MiB
  float*  part  = (float*)(ws + 131072 + 2097152);              // 2 MiB
  float*  cpart = (float*)(ws + 131072 + 2097152 + 2097152);    // 4 MiB
  __bf16* bkey  = (__bf16*)(ws + 131072 + 2097152 + 2097152 + 4194304);  // 128 MiB
  const size_t need = 131072ull + 2097152 + 2097152 + 4194304 + 134217728;

  convert_ua_kernel<<<512, 256, 0, stream>>>(Uaw, ubt);
  qc_kernel<<<dim3(4, 32), 256, 0, stream>>>(q, Waw, Wab, Uab, qc);
  if (ws_size >= need) {
    convert_key_kernel<<<4096, 256, 0, stream>>>(key, bkey);
    gemm_scores_bf16_kernel<<<4096, 256, 0, stream>>>(bkey, ubt, qc, vaw, part);
    softmax_kernel<<<32, 256, 0, stream>>>(part, out);
    ctx_part_bf16_kernel<<<dim3(16, 32), 256, 0, stream>>>(bkey, out, cpart);
    ctx_reduce_kernel<<<128, 256, 0, stream>>>(cpart, out, 16);
  } else {
    gemm_scores_kernel<<<4096, 256, 0, stream>>>(key, ubt, qc, vaw, part);
    softmax_kernel<<<32, 256, 0, stream>>>(part, out);
    ctx_part_kernel<<<dim3(32, 32), 256, 0, stream>>>(key, out, cpart);
    ctx_reduce_kernel<<<128, 256, 0, stream>>>(cpart, out, 32);
  }
}